// Round 4
// baseline (356.802 us; speedup 1.0000x reference)
//
#include <hip/hip_runtime.h>
#include <math.h>

// Problem constants (fixed shapes from the reference)
#define B_    8
#define HW_   25921        // 161*161
#define M_    128          // mask slots
#define G_    64           // GT slots
#define CP1_  134          // classes + 1
#define CLS_  133          // "no object" index = C
#define ALPHA_ 0.75f
#define EPS_   1e-5f
#define NCA_  128          // chunks per batch for kA (denominator pass)
#define MAXCHUNK 64

// ---------------------------------------------------------------------------
// kA: per-pixel softmax DENOMINATORS only. No atomics, no gt. float4 loads
// (2 pixels/wave-load), 5-level intra-32 shfl reduce, lane {0,32} store 1/s.
// Diagnostic: if this alone stays ~75+ us, the R3 wall is the load/shfl side.
// ---------------------------------------------------------------------------
__global__ __launch_bounds__(512) void kA_denom(
    const float* __restrict__ logits, float* __restrict__ invp)
{
  const int b = blockIdx.x / NCA_;
  const int k = blockIdx.x - b * NCA_;
  const int chunk = (HW_ + NCA_ - 1) / NCA_;   // 203
  const int p0 = k * chunk;
  const int p1 = min(p0 + chunk, HW_);
  const int wave = threadIdx.x >> 6, lane = threadIdx.x & 63;
  const int half = lane >> 5, l31 = lane & 31;
  const float* Lb = logits + (size_t)b * HW_ * M_;
  float* ib = invp + (size_t)b * HW_;

  for (int base = p0 + wave * 8; base < p1; base += 64) {
    float4 v[4]; bool act[4]; int pcs[4];
    #pragma unroll
    for (int q = 0; q < 4; ++q) {
      const int p = base + 2 * q + half;
      act[q] = p < p1;
      const int pc = act[q] ? p : (p1 - 1);
      pcs[q] = pc;
      v[q] = *(const float4*)(Lb + (size_t)pc * M_ + l31 * 4);
    }
    float s[4];
    #pragma unroll
    for (int q = 0; q < 4; ++q) {
      // same arithmetic order as R3 (bit-identical inter downstream)
      s[q] = (__expf(v[q].x) + __expf(v[q].y)) + (__expf(v[q].z) + __expf(v[q].w));
    }
    #pragma unroll
    for (int o = 16; o; o >>= 1) {
      #pragma unroll
      for (int q = 0; q < 4; ++q) s[q] += __shfl_xor(s[q], o);
    }
    #pragma unroll
    for (int q = 0; q < 4; ++q)
      if (l31 == 0 && act[q]) ib[pcs[q]] = 1.0f / s[q];
  }
}

// ---------------------------------------------------------------------------
// kB: scatter pass. Re-reads logits (L3-warm), loads 1/denom, no cross-lane
// ops at all: load -> expf -> mul -> ds_add. acc layout [c][row][m>>2] as R3.
// Diagnostic: if this alone stays ~75+ us, the R3 wall is the LDS-atomic side.
// ---------------------------------------------------------------------------
__global__ __launch_bounds__(1024) void kB_scatter(
    const float* __restrict__ logits, const float* __restrict__ invp,
    const int* __restrict__ gt, float* __restrict__ partial,
    int nchunk, int chunk)
{
  __shared__ float acc[4 * G_ * 32];   // 32 KB
  __shared__ int   gtL[824];
  const int tid = threadIdx.x;
  const int b = blockIdx.x / nchunk;
  const int k = blockIdx.x - b * nchunk;
  const int p0 = k * chunk;
  const int p1 = min(p0 + chunk, HW_);
  const int n = p1 - p0;

  for (int i = tid; i < 4 * G_ * 32; i += 1024) acc[i] = 0.f;
  const int* gtb = gt + (size_t)b * HW_;
  for (int i = tid; i < n; i += 1024) gtL[i] = gtb[p0 + i];
  __syncthreads();

  const int wave = tid >> 6, lane = tid & 63;
  const int half = lane >> 5, l31 = lane & 31;
  const float* Lb = logits + (size_t)b * HW_ * M_;
  const float* ib = invp + (size_t)b * HW_;

  for (int base = p0 + wave * 8; base < p1; base += 128) {
    float4 v[4]; float iv[4]; int row[4]; bool act[4];
    #pragma unroll
    for (int q = 0; q < 4; ++q) {
      const int p = base + 2 * q + half;
      act[q] = p < p1;
      const int pc = act[q] ? p : (p1 - 1);
      v[q] = *(const float4*)(Lb + (size_t)pc * M_ + l31 * 4);
      iv[q] = ib[pc];
      row[q] = gtL[pc - p0];
    }
    #pragma unroll
    for (int q = 0; q < 4; ++q) {
      if (act[q]) {
        const int bi = row[q] * 32 + l31;
        atomicAdd(&acc[0 * 2048 + bi], __expf(v[q].x) * iv[q]);
        atomicAdd(&acc[1 * 2048 + bi], __expf(v[q].y) * iv[q]);
        atomicAdd(&acc[2 * 2048 + bi], __expf(v[q].z) * iv[q]);
        atomicAdd(&acc[3 * 2048 + bi], __expf(v[q].w) * iv[q]);
      }
    }
  }
  __syncthreads();
  float* outp = partial + (size_t)blockIdx.x * (G_ * M_);
  for (int i = tid; i < G_ * M_; i += 1024) {
    const int g = i >> 7, m = i & 127;
    outp[i] = acc[(m & 3) * 2048 + g * 32 + (m >> 2)];
  }
}

// ---------------------------------------------------------------------------
// K2: reduce partials -> inter[b][g][m]. One block per (b,g).
// ---------------------------------------------------------------------------
__global__ __launch_bounds__(128) void k2_reduce(
    const float* __restrict__ partial, float* __restrict__ inter, int nchunk)
{
  const int b = blockIdx.x >> 6;
  const int g = blockIdx.x & 63;
  const int m = threadIdx.x;
  float s = 0.f;
  for (int k = 0; k < nchunk; ++k)
    s += partial[((size_t)(b * nchunk + k) * G_ + g) * M_ + m];
  inter[((size_t)b * G_ + g) * M_ + m] = s;
}

// ---------------------------------------------------------------------------
// K4: per batch. Same algorithm path as R3 (row-min u, column reduction v,
// column-argmin greedy, shifted-minv SSP with live duals, first-index ties)
// so the matching tie-vertex is preserved. Perf-only changes:
//  - argmin via index-embedded-in-mantissa fmin_f64 chain (ties <2^-45 only)
//  - exact delta fetched from owner lane (2 shfl)
//  - prow prefetch merged with the break check
// ---------------------------------------------------------------------------
#define ISTR 130   // interL stride
#define CSTR 129   // cost/expS stride

__device__ __forceinline__ double embed_idx(double a, int idx) {
  long long bl = __double_as_longlong(a);
  bl = (bl & ~0xFFll) | (long long)idx;
  return __longlong_as_double(bl);
}

__global__ __launch_bounds__(1024) void k4_match_loss(
    const float* __restrict__ inter, const float* __restrict__ cl,
    const int* __restrict__ semmap, float* __restrict__ out)
{
  __shared__ float interL[G_ * ISTR];
  __shared__ float expSL[48 * CSTR];
  __shared__ float costL[48 * CSTR];
  __shared__ float lseL[M_], negceL[M_], sumpredL[M_], cntL[G_];
  __shared__ int   semL[G_], validg[G_];
  __shared__ int   ivA[M_], prowA[M_], colofL[G_];
  __shared__ int   nvL, nvtotL;

  const int tid = threadIdx.x;
  const int b = blockIdx.x;
  const int lane = tid & 63, wave = tid >> 6;

  // ---- Phase A: semL, interL load, class log-softmax (lse/negce) ----
  if (tid < G_) semL[tid] = semmap[b * G_ + tid];
  for (int i = tid; i < G_ * M_; i += 1024) {
    const int g = i >> 7, m = i & 127;
    interL[g * ISTR + m] = inter[(size_t)b * G_ * M_ + i];
  }
  for (int r = wave; r < M_; r += 16) {
    const float* x = cl + ((size_t)b * M_ + r) * CP1_;
    float a = x[lane];
    float bb = (lane + 64  < CP1_) ? x[lane + 64]  : -1e30f;
    float cc = (lane + 128 < CP1_) ? x[lane + 128] : -1e30f;
    float mx = fmaxf(a, fmaxf(bb, cc));
    #pragma unroll
    for (int o = 32; o; o >>= 1) mx = fmaxf(mx, __shfl_xor(mx, o));
    float s = __expf(a - mx);
    if (lane + 64  < CP1_) s += __expf(bb - mx);
    if (lane + 128 < CP1_) s += __expf(cc - mx);
    #pragma unroll
    for (int o = 32; o; o >>= 1) s += __shfl_xor(s, o);
    const float lse = mx + logf(s);
    if (lane == 0) lseL[r] = lse;
    if (lane == CLS_ - 128) negceL[r] = lse - cc;   // -log_prob[.., C]
  }
  __syncthreads();

  // ---- Phase A2: wave 0: validg/nv + nvtot ----
  if (wave == 0) {
    const int sv = semL[tid];
    const unsigned long long vm = __ballot(sv >= 0);
    if (sv >= 0) {
      const int rank = __popcll(vm & ((1ull << tid) - 1ull));
      validg[rank] = tid;
    }
    if (tid == 0) nvL = (int)__popcll(vm);
    int c = 0;
    #pragma unroll
    for (int kk = 0; kk < (B_ * G_) / 64; ++kk)
      c += (semmap[tid + 64 * kk] >= 0) ? 1 : 0;
    #pragma unroll
    for (int o = 32; o; o >>= 1) c += __shfl_xor(c, o);
    if (tid == 0) nvtotL = c;
  }
  __syncthreads();
  const int nv = min(nvL, 48);

  // ---- Phase B1: sumpred, cnt, expS ----
  if (tid < M_) {
    float s = 0.f;
    for (int g = 0; g < G_; ++g) s += interL[g * ISTR + tid];
    sumpredL[tid] = s;
  } else if (tid < M_ + G_) {
    const int g = tid - M_;
    float s = 0.f;
    for (int m = 0; m < M_; ++m) s += interL[g * ISTR + m];
    cntL[g] = s;
  } else if (tid >= 256) {
    for (int i = tid - 256; i < nv * M_; i += 768) {
      const int r = i >> 7, m = i & 127;
      const int sem = semL[validg[r]];
      expSL[r * CSTR + m] =
        __expf(cl[((size_t)b * M_ + m) * CP1_ + sem] - lseL[m]);
    }
  }
  __syncthreads();

  // ---- Phase B2: cost ----
  for (int i = tid; i < nv * M_; i += 1024) {
    const int r = i >> 7, m = i & 127;
    const int g = validg[r];
    const float dice = interL[g * ISTR + m] /
                       ((cntL[g] + sumpredL[m]) * 0.5f + EPS_);
    costL[r * CSTR + m] = -(expSL[r * CSTR + m] * dice);
  }
  __syncthreads();

  if (wave != 0) return;
  const int t = tid;   // 0..63

  // ---- JV init (identical to R3): u=rowmin, v=col reduction, greedy ----
  double u_reg = 0.0;
  if (t < nv) {
    float bv = 1e30f;
    for (int m = 0; m < M_; ++m) {
      const float c = costL[t * CSTR + m];
      if (c < bv) bv = c;
    }
    u_reg = (double)bv;
  }
  double v0d = 0.0, v1d = 0.0;
  {
    double m0 = 1e18, m1 = 1e18; int i0 = 0, i1 = 0;
    for (int i = 0; i < nv; ++i) {
      const double ui = __shfl(u_reg, i);
      const double c0 = (double)costL[i * CSTR + t] - ui;
      const double c1 = (double)costL[i * CSTR + t + 64] - ui;
      if (c0 < m0) { m0 = c0; i0 = i; }
      if (c1 < m1) { m1 = c1; i1 = i; }
    }
    v0d = m0; v1d = m1;
    ivA[t] = i0; ivA[t + 64] = i1;
  }
  prowA[t] = 0; prowA[t + 64] = 0;
  if (t < G_) colofL[t] = -1;
  if (t == 0) {
    unsigned long long rowfree = (nv < 64) ? ((1ull << nv) - 1ull) : ~0ull;
    for (int j = 0; j < M_; ++j) {
      const int r = ivA[j];
      if ((rowfree >> r) & 1ull) {
        rowfree &= ~(1ull << r);
        prowA[j] = r + 1;
        colofL[r] = j;
      }
    }
  }
  unsigned long long um = __ballot(t < nv && colofL[t] < 0);

  // ---- SSP for remaining free rows ----
  int way0, way1;
  while (um) {
    const int iRow = (int)__builtin_ctzll(um) + 1;
    um &= um - 1;
    double minv0 = 1e18, minv1 = 1e18;
    bool used0 = false, used1 = false;
    bool inTree = false;
    way0 = 0; way1 = 0;
    int j0 = 0, i0 = iRow;
    for (int guard = 0; guard < 2 * M_ + 4; ++guard) {
      if (j0 != 0) {
        const int src = (j0 - 1) & 63, hi = (j0 - 1) >> 6;
        if (t == src) { if (hi) used1 = true; else used0 = true; }
      }
      if (t == i0 - 1) inTree = true;
      const double ui0 = __shfl(u_reg, i0 - 1);
      const float c0 = costL[(i0 - 1) * CSTR + t];
      const float c1 = costL[(i0 - 1) * CSTR + t + 64];
      if (!used0) { const double cur = (double)c0 - ui0 - v0d; if (cur < minv0) { minv0 = cur; way0 = j0; } }
      if (!used1) { const double cur = (double)c1 - ui0 - v1d; if (cur < minv1) { minv1 = cur; way1 = j0; } }
      // packed argmin: index embedded in low 8 mantissa bits, fmin chain.
      // First-index on exact ties (== np.argmin); deviates only for
      // near-ties < 2^-45 relative (accepted).
      const double a0 = used0 ? 1e18 : minv0;
      const double a1 = used1 ? 1e18 : minv1;
      double pk = fmin(embed_idx(a0, t + 1), embed_idx(a1, t + 65));
      #pragma unroll
      for (int o = 32; o; o >>= 1) pk = fmin(pk, __shfl_xor(pk, o));
      const int j1 = (int)(__double_as_longlong(pk) & 0xFF);
      const int src1 = (j1 - 1) & 63, hi1 = (j1 - 1) >> 6;
      const double d0s = __shfl(minv0, src1);
      const double d1s = __shfl(minv1, src1);
      const double delta = hi1 ? d1s : d0s;       // exact minv[j1]
      const int pr = prowA[j1 - 1];               // prefetch + break check
      if (used0) v0d -= delta; else minv0 -= delta;
      if (used1) v1d -= delta; else minv1 -= delta;
      if (inTree) u_reg += delta;
      j0 = j1;
      if (pr == 0) break;
      i0 = pr;
    }
    // augment along 'way' chain
    int j = j0;
    for (int guard = 0; guard <= M_ && j; ++guard) {
      const int src = (j - 1) & 63, hi = (j - 1) >> 6;
      const int wl = __shfl(way0, src), wh = __shfl(way1, src);
      const int jp = hi ? wh : wl;
      const int newr = (jp == 0) ? iRow : prowA[jp - 1];
      if (t == 0) prowA[j - 1] = newr;
      j = jp;
    }
  }

  // ---- Loss epilogue ----
  double clsum = 0.0, dsum = 0.0;
  #pragma unroll
  for (int h = 0; h < 2; ++h) {
    const int m = t + 64 * h;
    const int pr = prowA[m];
    const float* lpbm = cl + ((size_t)b * M_ + m) * CP1_;
    if (pr > 0) {
      const int r = pr - 1;
      const int g = validg[r];
      const float md = interL[g * ISTR + m] /
                       ((cntL[g] + sumpredL[m]) * 0.5f + EPS_);
      const float lpx = lpbm[semL[g]] - lseL[m];
      const float es = expSL[r * CSTR + m];
      clsum += (double)(ALPHA_ * md * (-lpx));            // alpha*dice*pos_ce
      dsum  += (double)(-es * logf(md + EPS_));           // -cls*log(dice+eps)
    } else {
      clsum += (double)((1.0f - ALPHA_) * negceL[m]);     // 0.25 * neg_ce
    }
  }
  #pragma unroll
  for (int o = 32; o; o >>= 1) {
    clsum += __shfl_xor(clsum, o);
    dsum  += __shfl_xor(dsum, o);
  }
  if (t == 0) {
    const float contrib = (float)(clsum / (double)(B_ * M_) +
                                  dsum / (double)(nvtotL + 1));
    atomicAdd(out, contrib);
  }
}

// ---------------------------------------------------------------------------
extern "C" void kernel_launch(void* const* d_in, const int* in_sizes, int n_in,
                              void* d_out, int out_size, void* d_ws, size_t ws_size,
                              hipStream_t stream) {
  const float* logits = (const float*)d_in[0];
  const float* cl     = (const float*)d_in[1];
  const int*   gt     = (const int*)d_in[2];
  const int*   semmap = (const int*)d_in[3];
  float* out = (float*)d_out;

  // workspace layout (floats): invp | partial | inter
  const size_t inv_f   = (size_t)B_ * HW_;
  const size_t inter_f = (size_t)B_ * G_ * M_;
  const size_t fixed_f = inv_f + inter_f;
  const size_t per_chunk_f = (size_t)B_ * G_ * M_;
  int nchunk = MAXCHUNK;
  if (ws_size < (fixed_f + (size_t)MAXCHUNK * per_chunk_f) * sizeof(float)) {
    size_t avail = ws_size / sizeof(float);
    size_t nc = (avail > fixed_f) ? (avail - fixed_f) / per_chunk_f : 1;
    nchunk = (int)(nc < 1 ? 1 : (nc > MAXCHUNK ? MAXCHUNK : nc));
    if (nchunk < 32) nchunk = 32;   // gtL sized for chunk <= 824
  }
  const int chunk = (HW_ + nchunk - 1) / nchunk;

  float* ws      = (float*)d_ws;
  float* invp    = ws;
  float* partial = invp + inv_f;
  float* inter   = partial + (size_t)B_ * nchunk * G_ * M_;

  hipMemsetAsync(d_out, 0, sizeof(float), stream);
  hipLaunchKernelGGL(kA_denom, dim3(B_ * NCA_), dim3(512), 0, stream,
                     logits, invp);
  hipLaunchKernelGGL(kB_scatter, dim3(B_ * nchunk), dim3(1024), 0, stream,
                     logits, invp, gt, partial, nchunk, chunk);
  hipLaunchKernelGGL(k2_reduce, dim3(B_ * G_), dim3(128), 0, stream,
                     partial, inter, nchunk);
  hipLaunchKernelGGL(k4_match_loss, dim3(B_), dim3(1024), 0, stream,
                     inter, cl, semmap, out);
}

// Round 5
// 226.227 us; speedup vs baseline: 1.5772x; 1.5772x over previous
//
#include <hip/hip_runtime.h>
#include <math.h>

// Problem constants (fixed shapes from the reference)
#define B_    8
#define HW_   25921        // 161*161
#define M_    128          // mask slots
#define G_    64           // GT slots
#define CP1_  134          // classes + 1
#define CLS_  133          // "no object" index = C
#define ALPHA_ 0.75f
#define EPS_   1e-5f

// ---------------------------------------------------------------------------
// kH: counting-sort pixel indices by gt value. One block per batch.
// INT LDS atomics only (native ds_add_u32). 4 sub-histograms cut contention.
// Outputs: ordered[b][HW_] pixel indices grouped by g, baseg[b][G_+1] offsets.
// ---------------------------------------------------------------------------
__global__ __launch_bounds__(1024) void kH_bucket(
    const int* __restrict__ gt, int* __restrict__ ordered,
    int* __restrict__ baseg)
{
  __shared__ int cnt[4][G_];
  __shared__ int off[G_];
  const int tid = threadIdx.x;
  const int b = blockIdx.x;
  const int lane = tid & 63, wave = tid >> 6;
  const int* gtb = gt + (size_t)b * HW_;

  for (int i = tid; i < 4 * G_; i += 1024) ((int*)cnt)[i] = 0;
  __syncthreads();
  for (int i = tid; i < HW_; i += 1024)
    atomicAdd(&cnt[tid & 3][gtb[i]], 1);
  __syncthreads();

  if (wave == 0) {
    const int c = cnt[0][lane] + cnt[1][lane] + cnt[2][lane] + cnt[3][lane];
    int inc = c;
    #pragma unroll
    for (int o = 1; o < 64; o <<= 1) {
      const int n = __shfl_up(inc, o);
      if (lane >= o) inc += n;
    }
    const int ex = inc - c;                  // exclusive prefix
    off[lane] = ex;
    baseg[b * (G_ + 1) + lane] = ex;
    if (lane == 63) baseg[b * (G_ + 1) + G_] = ex + c;
  }
  __syncthreads();

  int* ob = ordered + (size_t)b * HW_;
  for (int i = tid; i < HW_; i += 1024) {
    const int g = gtb[i];
    const int pos = atomicAdd(&off[g], 1);
    ob[pos] = i;
  }
}

// ---------------------------------------------------------------------------
// kS: gather pass. One block per (b,g). Waves walk the g's pixel list; each
// pixel's 512B logits row is one fully-coalesced float2/lane load; denominator
// via 6-level intra-wave shfl (8 interleaved chains); accumulate e/s into
// REGISTERS. Deterministic LDS tree combine -> inter[b,g,:]. No fp atomics.
// ---------------------------------------------------------------------------
__global__ __launch_bounds__(1024) void kS_gather(
    const float* __restrict__ logits, const int* __restrict__ ordered,
    const int* __restrict__ baseg, float* __restrict__ inter)
{
  __shared__ float red[16][130];
  const int tid = threadIdx.x;
  const int g = blockIdx.x & 63;
  const int b = blockIdx.x >> 6;
  const int lane = tid & 63, wave = tid >> 6;

  const int s0 = baseg[b * (G_ + 1) + g];
  const int s1 = baseg[b * (G_ + 1) + g + 1];
  const int* lst = ordered + (size_t)b * HW_;
  const float* Lb = logits + (size_t)b * HW_ * M_;

  float accx = 0.f, accy = 0.f;
  for (int i = s0 + wave * 8; i < s1; i += 128) {
    bool act[8]; float2 v[8];
    #pragma unroll
    for (int q = 0; q < 8; ++q) {
      act[q] = (i + q) < s1;
      const int idx = lst[act[q] ? (i + q) : (s1 - 1)];
      v[q] = ((const float2*)(Lb + (size_t)idx * M_))[lane];
    }
    float e0[8], e1[8], s[8];
    #pragma unroll
    for (int q = 0; q < 8; ++q) {
      e0[q] = __expf(v[q].x); e1[q] = __expf(v[q].y);
      s[q] = e0[q] + e1[q];
    }
    #pragma unroll
    for (int o = 32; o; o >>= 1) {     // 8 interleaved chains hide shfl latency
      #pragma unroll
      for (int q = 0; q < 8; ++q) s[q] += __shfl_xor(s[q], o);
    }
    #pragma unroll
    for (int q = 0; q < 8; ++q) {
      if (act[q]) {
        const float inv = 1.0f / s[q];
        accx += e0[q] * inv;
        accy += e1[q] * inv;
      }
    }
  }
  red[wave][2 * lane]     = accx;
  red[wave][2 * lane + 1] = accy;
  __syncthreads();
  if (tid < M_) {
    float s = 0.f;
    #pragma unroll
    for (int w = 0; w < 16; ++w) s += red[w][tid];
    inter[((size_t)b * G_ + g) * M_ + tid] = s;
  }
}

// ---------------------------------------------------------------------------
// K4: UNCHANGED from R4 (preserves the absmax=0.015625 matching path).
// Per batch: LDS cost build, JV init (row-min u, col reduction v, greedy),
// SSP with packed fmin_f64 argmin, loss epilogue -> atomicAdd(out).
// ---------------------------------------------------------------------------
#define ISTR 130   // interL stride
#define CSTR 129   // cost/expS stride

__device__ __forceinline__ double embed_idx(double a, int idx) {
  long long bl = __double_as_longlong(a);
  bl = (bl & ~0xFFll) | (long long)idx;
  return __longlong_as_double(bl);
}

__global__ __launch_bounds__(1024) void k4_match_loss(
    const float* __restrict__ inter, const float* __restrict__ cl,
    const int* __restrict__ semmap, float* __restrict__ out)
{
  __shared__ float interL[G_ * ISTR];
  __shared__ float expSL[48 * CSTR];
  __shared__ float costL[48 * CSTR];
  __shared__ float lseL[M_], negceL[M_], sumpredL[M_], cntL[G_];
  __shared__ int   semL[G_], validg[G_];
  __shared__ int   ivA[M_], prowA[M_], colofL[G_];
  __shared__ int   nvL, nvtotL;

  const int tid = threadIdx.x;
  const int b = blockIdx.x;
  const int lane = tid & 63, wave = tid >> 6;

  // ---- Phase A: semL, interL load, class log-softmax (lse/negce) ----
  if (tid < G_) semL[tid] = semmap[b * G_ + tid];
  for (int i = tid; i < G_ * M_; i += 1024) {
    const int g = i >> 7, m = i & 127;
    interL[g * ISTR + m] = inter[(size_t)b * G_ * M_ + i];
  }
  for (int r = wave; r < M_; r += 16) {
    const float* x = cl + ((size_t)b * M_ + r) * CP1_;
    float a = x[lane];
    float bb = (lane + 64  < CP1_) ? x[lane + 64]  : -1e30f;
    float cc = (lane + 128 < CP1_) ? x[lane + 128] : -1e30f;
    float mx = fmaxf(a, fmaxf(bb, cc));
    #pragma unroll
    for (int o = 32; o; o >>= 1) mx = fmaxf(mx, __shfl_xor(mx, o));
    float s = __expf(a - mx);
    if (lane + 64  < CP1_) s += __expf(bb - mx);
    if (lane + 128 < CP1_) s += __expf(cc - mx);
    #pragma unroll
    for (int o = 32; o; o >>= 1) s += __shfl_xor(s, o);
    const float lse = mx + logf(s);
    if (lane == 0) lseL[r] = lse;
    if (lane == CLS_ - 128) negceL[r] = lse - cc;   // -log_prob[.., C]
  }
  __syncthreads();

  // ---- Phase A2: wave 0: validg/nv + nvtot ----
  if (wave == 0) {
    const int sv = semL[tid];
    const unsigned long long vm = __ballot(sv >= 0);
    if (sv >= 0) {
      const int rank = __popcll(vm & ((1ull << tid) - 1ull));
      validg[rank] = tid;
    }
    if (tid == 0) nvL = (int)__popcll(vm);
    int c = 0;
    #pragma unroll
    for (int kk = 0; kk < (B_ * G_) / 64; ++kk)
      c += (semmap[tid + 64 * kk] >= 0) ? 1 : 0;
    #pragma unroll
    for (int o = 32; o; o >>= 1) c += __shfl_xor(c, o);
    if (tid == 0) nvtotL = c;
  }
  __syncthreads();
  const int nv = min(nvL, 48);

  // ---- Phase B1: sumpred, cnt, expS ----
  if (tid < M_) {
    float s = 0.f;
    for (int g = 0; g < G_; ++g) s += interL[g * ISTR + tid];
    sumpredL[tid] = s;
  } else if (tid < M_ + G_) {
    const int g = tid - M_;
    float s = 0.f;
    for (int m = 0; m < M_; ++m) s += interL[g * ISTR + m];
    cntL[g] = s;
  } else if (tid >= 256) {
    for (int i = tid - 256; i < nv * M_; i += 768) {
      const int r = i >> 7, m = i & 127;
      const int sem = semL[validg[r]];
      expSL[r * CSTR + m] =
        __expf(cl[((size_t)b * M_ + m) * CP1_ + sem] - lseL[m]);
    }
  }
  __syncthreads();

  // ---- Phase B2: cost ----
  for (int i = tid; i < nv * M_; i += 1024) {
    const int r = i >> 7, m = i & 127;
    const int g = validg[r];
    const float dice = interL[g * ISTR + m] /
                       ((cntL[g] + sumpredL[m]) * 0.5f + EPS_);
    costL[r * CSTR + m] = -(expSL[r * CSTR + m] * dice);
  }
  __syncthreads();

  if (wave != 0) return;
  const int t = tid;   // 0..63

  // ---- JV init: u=rowmin, v=col reduction, greedy tight assignment ----
  double u_reg = 0.0;
  if (t < nv) {
    float bv = 1e30f;
    for (int m = 0; m < M_; ++m) {
      const float c = costL[t * CSTR + m];
      if (c < bv) bv = c;
    }
    u_reg = (double)bv;
  }
  double v0d = 0.0, v1d = 0.0;
  {
    double m0 = 1e18, m1 = 1e18; int i0 = 0, i1 = 0;
    for (int i = 0; i < nv; ++i) {
      const double ui = __shfl(u_reg, i);
      const double c0 = (double)costL[i * CSTR + t] - ui;
      const double c1 = (double)costL[i * CSTR + t + 64] - ui;
      if (c0 < m0) { m0 = c0; i0 = i; }
      if (c1 < m1) { m1 = c1; i1 = i; }
    }
    v0d = m0; v1d = m1;
    ivA[t] = i0; ivA[t + 64] = i1;
  }
  prowA[t] = 0; prowA[t + 64] = 0;
  if (t < G_) colofL[t] = -1;
  if (t == 0) {
    unsigned long long rowfree = (nv < 64) ? ((1ull << nv) - 1ull) : ~0ull;
    for (int j = 0; j < M_; ++j) {
      const int r = ivA[j];
      if ((rowfree >> r) & 1ull) {
        rowfree &= ~(1ull << r);
        prowA[j] = r + 1;
        colofL[r] = j;
      }
    }
  }
  unsigned long long um = __ballot(t < nv && colofL[t] < 0);

  // ---- SSP for remaining free rows ----
  int way0, way1;
  while (um) {
    const int iRow = (int)__builtin_ctzll(um) + 1;
    um &= um - 1;
    double minv0 = 1e18, minv1 = 1e18;
    bool used0 = false, used1 = false;
    bool inTree = false;
    way0 = 0; way1 = 0;
    int j0 = 0, i0 = iRow;
    for (int guard = 0; guard < 2 * M_ + 4; ++guard) {
      if (j0 != 0) {
        const int src = (j0 - 1) & 63, hi = (j0 - 1) >> 6;
        if (t == src) { if (hi) used1 = true; else used0 = true; }
      }
      if (t == i0 - 1) inTree = true;
      const double ui0 = __shfl(u_reg, i0 - 1);
      const float c0 = costL[(i0 - 1) * CSTR + t];
      const float c1 = costL[(i0 - 1) * CSTR + t + 64];
      if (!used0) { const double cur = (double)c0 - ui0 - v0d; if (cur < minv0) { minv0 = cur; way0 = j0; } }
      if (!used1) { const double cur = (double)c1 - ui0 - v1d; if (cur < minv1) { minv1 = cur; way1 = j0; } }
      const double a0 = used0 ? 1e18 : minv0;
      const double a1 = used1 ? 1e18 : minv1;
      double pk = fmin(embed_idx(a0, t + 1), embed_idx(a1, t + 65));
      #pragma unroll
      for (int o = 32; o; o >>= 1) pk = fmin(pk, __shfl_xor(pk, o));
      const int j1 = (int)(__double_as_longlong(pk) & 0xFF);
      const int src1 = (j1 - 1) & 63, hi1 = (j1 - 1) >> 6;
      const double d0s = __shfl(minv0, src1);
      const double d1s = __shfl(minv1, src1);
      const double delta = hi1 ? d1s : d0s;       // exact minv[j1]
      const int pr = prowA[j1 - 1];               // prefetch + break check
      if (used0) v0d -= delta; else minv0 -= delta;
      if (used1) v1d -= delta; else minv1 -= delta;
      if (inTree) u_reg += delta;
      j0 = j1;
      if (pr == 0) break;
      i0 = pr;
    }
    // augment along 'way' chain
    int j = j0;
    for (int guard = 0; guard <= M_ && j; ++guard) {
      const int src = (j - 1) & 63, hi = (j - 1) >> 6;
      const int wl = __shfl(way0, src), wh = __shfl(way1, src);
      const int jp = hi ? wh : wl;
      const int newr = (jp == 0) ? iRow : prowA[jp - 1];
      if (t == 0) prowA[j - 1] = newr;
      j = jp;
    }
  }

  // ---- Loss epilogue ----
  double clsum = 0.0, dsum = 0.0;
  #pragma unroll
  for (int h = 0; h < 2; ++h) {
    const int m = t + 64 * h;
    const int pr = prowA[m];
    const float* lpbm = cl + ((size_t)b * M_ + m) * CP1_;
    if (pr > 0) {
      const int r = pr - 1;
      const int g = validg[r];
      const float md = interL[g * ISTR + m] /
                       ((cntL[g] + sumpredL[m]) * 0.5f + EPS_);
      const float lpx = lpbm[semL[g]] - lseL[m];
      const float es = expSL[r * CSTR + m];
      clsum += (double)(ALPHA_ * md * (-lpx));            // alpha*dice*pos_ce
      dsum  += (double)(-es * logf(md + EPS_));           // -cls*log(dice+eps)
    } else {
      clsum += (double)((1.0f - ALPHA_) * negceL[m]);     // 0.25 * neg_ce
    }
  }
  #pragma unroll
  for (int o = 32; o; o >>= 1) {
    clsum += __shfl_xor(clsum, o);
    dsum  += __shfl_xor(dsum, o);
  }
  if (t == 0) {
    const float contrib = (float)(clsum / (double)(B_ * M_) +
                                  dsum / (double)(nvtotL + 1));
    atomicAdd(out, contrib);
  }
}

// ---------------------------------------------------------------------------
extern "C" void kernel_launch(void* const* d_in, const int* in_sizes, int n_in,
                              void* d_out, int out_size, void* d_ws, size_t ws_size,
                              hipStream_t stream) {
  const float* logits = (const float*)d_in[0];
  const float* cl     = (const float*)d_in[1];
  const int*   gt     = (const int*)d_in[2];
  const int*   semmap = (const int*)d_in[3];
  float* out = (float*)d_out;

  // workspace layout: ordered (ints) | baseg (ints) | inter (floats)
  int*   ordered = (int*)d_ws;
  int*   baseg   = ordered + (size_t)B_ * HW_;
  float* inter   = (float*)(baseg + B_ * (G_ + 1));

  hipMemsetAsync(d_out, 0, sizeof(float), stream);
  hipLaunchKernelGGL(kH_bucket, dim3(B_), dim3(1024), 0, stream,
                     gt, ordered, baseg);
  hipLaunchKernelGGL(kS_gather, dim3(B_ * G_), dim3(1024), 0, stream,
                     logits, ordered, baseg, inter);
  hipLaunchKernelGGL(k4_match_loss, dim3(B_), dim3(1024), 0, stream,
                     inter, cl, semmap, out);
}

// Round 6
// 216.917 us; speedup vs baseline: 1.6449x; 1.0429x over previous
//
#include <hip/hip_runtime.h>
#include <math.h>

// Problem constants (fixed shapes from the reference)
#define B_    8
#define HW_   25921        // 161*161
#define M_    128          // mask slots
#define G_    64           // GT slots
#define CP1_  134          // classes + 1
#define CLS_  133          // "no object" index = C
#define ALPHA_ 0.75f
#define EPS_   1e-5f
#define NCH_  16           // chunks per batch for counting sort
#define CHSZ_ 1621         // ceil(HW_/NCH_)
#define LCAP_ 640          // LDS staging capacity per kS sub-block

// ---------------------------------------------------------------------------
// kH1: per-(b,chunk) histogram of gt values. 128 blocks. Int LDS atomics,
// 4 sub-histograms. -> cnts[b][c][G]
// ---------------------------------------------------------------------------
__global__ __launch_bounds__(256) void kH1_count(
    const int* __restrict__ gt, int* __restrict__ cnts)
{
  __shared__ int cnt[4][G_];
  const int tid = threadIdx.x;
  const int b = blockIdx.x >> 4, c = blockIdx.x & 15;
  const int p0 = c * CHSZ_, p1 = min(p0 + CHSZ_, HW_);
  const int* gtb = gt + (size_t)b * HW_;
  for (int i = tid; i < 4 * G_; i += 256) ((int*)cnt)[i] = 0;
  __syncthreads();
  for (int p = p0 + tid; p < p1; p += 256)
    atomicAdd(&cnt[tid & 3][gtb[p]], 1);
  __syncthreads();
  if (tid < G_)
    cnts[(blockIdx.x << 6) + tid] =
      cnt[0][tid] + cnt[1][tid] + cnt[2][tid] + cnt[3][tid];
}

// ---------------------------------------------------------------------------
// kH2: global per-(b,g) exclusive prefix -> baseg[b][G_+1]. One block.
// wave = b (8 waves), lane = g.
// ---------------------------------------------------------------------------
__global__ __launch_bounds__(512) void kH2_prefix(
    const int* __restrict__ cnts, int* __restrict__ baseg)
{
  const int b = threadIdx.x >> 6, g = threadIdx.x & 63;
  int tot = 0;
  #pragma unroll
  for (int c = 0; c < NCH_; ++c) tot += cnts[((b * NCH_ + c) << 6) + g];
  int inc = tot;
  #pragma unroll
  for (int o = 1; o < 64; o <<= 1) {
    const int n = __shfl_up(inc, o);
    if (g >= o) inc += n;
  }
  const int ex = inc - tot;
  baseg[b * (G_ + 1) + g] = ex;
  if (g == 63) baseg[b * (G_ + 1) + G_] = ex + tot;
}

// ---------------------------------------------------------------------------
// kH3: per-(b,chunk) scatter using base + per-chunk offsets. 128 blocks.
// ---------------------------------------------------------------------------
__global__ __launch_bounds__(256) void kH3_scatter(
    const int* __restrict__ gt, const int* __restrict__ cnts,
    const int* __restrict__ baseg, int* __restrict__ ordered)
{
  __shared__ int off[G_];
  const int tid = threadIdx.x;
  const int b = blockIdx.x >> 4, c = blockIdx.x & 15;
  const int p0 = c * CHSZ_, p1 = min(p0 + CHSZ_, HW_);
  const int* gtb = gt + (size_t)b * HW_;
  if (tid < G_) {
    int o = baseg[b * (G_ + 1) + tid];
    for (int cp = 0; cp < c; ++cp) o += cnts[((b * NCH_ + cp) << 6) + tid];
    off[tid] = o;
  }
  __syncthreads();
  int* ob = ordered + (size_t)b * HW_;
  for (int p = p0 + tid; p < p1; p += 256) {
    const int pos = atomicAdd(&off[gtb[p]], 1);
    ob[pos] = p;
  }
}

// ---------------------------------------------------------------------------
// kS: gather pass. 2 sub-blocks per (b,g); each stages its half of the pixel
// list into LDS (kills the dependent scalar-load chain), then per wave 8
// coalesced float2 row loads, inline denominator shfl-reduce, register acc,
// deterministic LDS tree -> interP[b][s][g][m]. No fp atomics anywhere.
// ---------------------------------------------------------------------------
__global__ __launch_bounds__(512) void kS_gather(
    const float* __restrict__ logits, const int* __restrict__ ordered,
    const int* __restrict__ baseg, float* __restrict__ interP)
{
  __shared__ float red[8][130];
  __shared__ int   lstL[LCAP_];
  const int tid = threadIdx.x;
  const int s = blockIdx.x & 1;
  const int g = (blockIdx.x >> 1) & 63;
  const int b = blockIdx.x >> 7;
  const int lane = tid & 63, wave = tid >> 6;

  const int s0 = baseg[b * (G_ + 1) + g];
  const int s1 = baseg[b * (G_ + 1) + g + 1];
  const int n = s1 - s0;
  const int half = (n + 1) >> 1;
  const int start = s0 + s * half;
  const int end = min(start + half, s1);
  const int cnt = end - start;
  const int* lst = ordered + (size_t)b * HW_ + start;
  const float* Lb = logits + (size_t)b * HW_ * M_;

  for (int i = tid; i < cnt && i < LCAP_; i += 512) lstL[i] = lst[i];
  __syncthreads();

  float accx = 0.f, accy = 0.f;
  for (int i = wave * 8; i < cnt; i += 64) {
    bool act[8]; float2 v[8];
    #pragma unroll
    for (int q = 0; q < 8; ++q) {
      act[q] = (i + q) < cnt;
      const int li = act[q] ? (i + q) : (cnt - 1);
      const int idx = (li < LCAP_) ? lstL[li] : lst[li];
      v[q] = ((const float2*)(Lb + (size_t)idx * M_))[lane];
    }
    float e0[8], e1[8], sm[8];
    #pragma unroll
    for (int q = 0; q < 8; ++q) {
      e0[q] = __expf(v[q].x); e1[q] = __expf(v[q].y);
      sm[q] = e0[q] + e1[q];
    }
    #pragma unroll
    for (int o = 32; o; o >>= 1) {     // 8 interleaved chains hide shfl latency
      #pragma unroll
      for (int q = 0; q < 8; ++q) sm[q] += __shfl_xor(sm[q], o);
    }
    #pragma unroll
    for (int q = 0; q < 8; ++q) {
      if (act[q]) {
        const float inv = 1.0f / sm[q];
        accx += e0[q] * inv;
        accy += e1[q] * inv;
      }
    }
  }
  red[wave][2 * lane]     = accx;
  red[wave][2 * lane + 1] = accy;
  __syncthreads();
  if (tid < M_) {
    float sv = 0.f;
    #pragma unroll
    for (int w = 0; w < 8; ++w) sv += red[w][tid];
    interP[(((size_t)b * 2 + s) * G_ + g) * M_ + tid] = sv;
  }
}

// ---------------------------------------------------------------------------
// K4: bit-identical algorithm to R4/R5 (preserves absmax=0.015625 vertex).
// Only the interL load now sums the two kS partials.
// ---------------------------------------------------------------------------
#define ISTR 130   // interL stride
#define CSTR 129   // cost/expS stride

__device__ __forceinline__ double embed_idx(double a, int idx) {
  long long bl = __double_as_longlong(a);
  bl = (bl & ~0xFFll) | (long long)idx;
  return __longlong_as_double(bl);
}

__global__ __launch_bounds__(1024) void k4_match_loss(
    const float* __restrict__ interP, const float* __restrict__ cl,
    const int* __restrict__ semmap, float* __restrict__ out)
{
  __shared__ float interL[G_ * ISTR];
  __shared__ float expSL[48 * CSTR];
  __shared__ float costL[48 * CSTR];
  __shared__ float lseL[M_], negceL[M_], sumpredL[M_], cntL[G_];
  __shared__ int   semL[G_], validg[G_];
  __shared__ int   ivA[M_], prowA[M_], colofL[G_];
  __shared__ int   nvL, nvtotL;

  const int tid = threadIdx.x;
  const int b = blockIdx.x;
  const int lane = tid & 63, wave = tid >> 6;

  // ---- Phase A: semL, interL load (sum 2 partials), class log-softmax ----
  if (tid < G_) semL[tid] = semmap[b * G_ + tid];
  {
    const float* ip0 = interP + (size_t)(b * 2 + 0) * G_ * M_;
    const float* ip1 = interP + (size_t)(b * 2 + 1) * G_ * M_;
    for (int i = tid; i < G_ * M_; i += 1024) {
      const int g = i >> 7, m = i & 127;
      interL[g * ISTR + m] = ip0[i] + ip1[i];
    }
  }
  for (int r = wave; r < M_; r += 16) {
    const float* x = cl + ((size_t)b * M_ + r) * CP1_;
    float a = x[lane];
    float bb = (lane + 64  < CP1_) ? x[lane + 64]  : -1e30f;
    float cc = (lane + 128 < CP1_) ? x[lane + 128] : -1e30f;
    float mx = fmaxf(a, fmaxf(bb, cc));
    #pragma unroll
    for (int o = 32; o; o >>= 1) mx = fmaxf(mx, __shfl_xor(mx, o));
    float s = __expf(a - mx);
    if (lane + 64  < CP1_) s += __expf(bb - mx);
    if (lane + 128 < CP1_) s += __expf(cc - mx);
    #pragma unroll
    for (int o = 32; o; o >>= 1) s += __shfl_xor(s, o);
    const float lse = mx + logf(s);
    if (lane == 0) lseL[r] = lse;
    if (lane == CLS_ - 128) negceL[r] = lse - cc;   // -log_prob[.., C]
  }
  __syncthreads();

  // ---- Phase A2: wave 0: validg/nv + nvtot ----
  if (wave == 0) {
    const int sv = semL[tid];
    const unsigned long long vm = __ballot(sv >= 0);
    if (sv >= 0) {
      const int rank = __popcll(vm & ((1ull << tid) - 1ull));
      validg[rank] = tid;
    }
    if (tid == 0) nvL = (int)__popcll(vm);
    int c = 0;
    #pragma unroll
    for (int kk = 0; kk < (B_ * G_) / 64; ++kk)
      c += (semmap[tid + 64 * kk] >= 0) ? 1 : 0;
    #pragma unroll
    for (int o = 32; o; o >>= 1) c += __shfl_xor(c, o);
    if (tid == 0) nvtotL = c;
  }
  __syncthreads();
  const int nv = min(nvL, 48);

  // ---- Phase B1: sumpred, cnt, expS ----
  if (tid < M_) {
    float s = 0.f;
    for (int g = 0; g < G_; ++g) s += interL[g * ISTR + tid];
    sumpredL[tid] = s;
  } else if (tid < M_ + G_) {
    const int g = tid - M_;
    float s = 0.f;
    for (int m = 0; m < M_; ++m) s += interL[g * ISTR + m];
    cntL[g] = s;
  } else if (tid >= 256) {
    for (int i = tid - 256; i < nv * M_; i += 768) {
      const int r = i >> 7, m = i & 127;
      const int sem = semL[validg[r]];
      expSL[r * CSTR + m] =
        __expf(cl[((size_t)b * M_ + m) * CP1_ + sem] - lseL[m]);
    }
  }
  __syncthreads();

  // ---- Phase B2: cost ----
  for (int i = tid; i < nv * M_; i += 1024) {
    const int r = i >> 7, m = i & 127;
    const int g = validg[r];
    const float dice = interL[g * ISTR + m] /
                       ((cntL[g] + sumpredL[m]) * 0.5f + EPS_);
    costL[r * CSTR + m] = -(expSL[r * CSTR + m] * dice);
  }
  __syncthreads();

  if (wave != 0) return;
  const int t = tid;   // 0..63

  // ---- JV init: u=rowmin, v=col reduction, greedy tight assignment ----
  double u_reg = 0.0;
  if (t < nv) {
    float bv = 1e30f;
    for (int m = 0; m < M_; ++m) {
      const float c = costL[t * CSTR + m];
      if (c < bv) bv = c;
    }
    u_reg = (double)bv;
  }
  double v0d = 0.0, v1d = 0.0;
  {
    double m0 = 1e18, m1 = 1e18; int i0 = 0, i1 = 0;
    for (int i = 0; i < nv; ++i) {
      const double ui = __shfl(u_reg, i);
      const double c0 = (double)costL[i * CSTR + t] - ui;
      const double c1 = (double)costL[i * CSTR + t + 64] - ui;
      if (c0 < m0) { m0 = c0; i0 = i; }
      if (c1 < m1) { m1 = c1; i1 = i; }
    }
    v0d = m0; v1d = m1;
    ivA[t] = i0; ivA[t + 64] = i1;
  }
  prowA[t] = 0; prowA[t + 64] = 0;
  if (t < G_) colofL[t] = -1;
  if (t == 0) {
    unsigned long long rowfree = (nv < 64) ? ((1ull << nv) - 1ull) : ~0ull;
    for (int j = 0; j < M_; ++j) {
      const int r = ivA[j];
      if ((rowfree >> r) & 1ull) {
        rowfree &= ~(1ull << r);
        prowA[j] = r + 1;
        colofL[r] = j;
      }
    }
  }
  unsigned long long um = __ballot(t < nv && colofL[t] < 0);

  // ---- SSP for remaining free rows ----
  int way0, way1;
  while (um) {
    const int iRow = (int)__builtin_ctzll(um) + 1;
    um &= um - 1;
    double minv0 = 1e18, minv1 = 1e18;
    bool used0 = false, used1 = false;
    bool inTree = false;
    way0 = 0; way1 = 0;
    int j0 = 0, i0 = iRow;
    for (int guard = 0; guard < 2 * M_ + 4; ++guard) {
      if (j0 != 0) {
        const int src = (j0 - 1) & 63, hi = (j0 - 1) >> 6;
        if (t == src) { if (hi) used1 = true; else used0 = true; }
      }
      if (t == i0 - 1) inTree = true;
      const double ui0 = __shfl(u_reg, i0 - 1);
      const float c0 = costL[(i0 - 1) * CSTR + t];
      const float c1 = costL[(i0 - 1) * CSTR + t + 64];
      if (!used0) { const double cur = (double)c0 - ui0 - v0d; if (cur < minv0) { minv0 = cur; way0 = j0; } }
      if (!used1) { const double cur = (double)c1 - ui0 - v1d; if (cur < minv1) { minv1 = cur; way1 = j0; } }
      const double a0 = used0 ? 1e18 : minv0;
      const double a1 = used1 ? 1e18 : minv1;
      double pk = fmin(embed_idx(a0, t + 1), embed_idx(a1, t + 65));
      #pragma unroll
      for (int o = 32; o; o >>= 1) pk = fmin(pk, __shfl_xor(pk, o));
      const int j1 = (int)(__double_as_longlong(pk) & 0xFF);
      const int src1 = (j1 - 1) & 63, hi1 = (j1 - 1) >> 6;
      const double d0s = __shfl(minv0, src1);
      const double d1s = __shfl(minv1, src1);
      const double delta = hi1 ? d1s : d0s;       // exact minv[j1]
      const int pr = prowA[j1 - 1];               // prefetch + break check
      if (used0) v0d -= delta; else minv0 -= delta;
      if (used1) v1d -= delta; else minv1 -= delta;
      if (inTree) u_reg += delta;
      j0 = j1;
      if (pr == 0) break;
      i0 = pr;
    }
    // augment along 'way' chain
    int j = j0;
    for (int guard = 0; guard <= M_ && j; ++guard) {
      const int src = (j - 1) & 63, hi = (j - 1) >> 6;
      const int wl = __shfl(way0, src), wh = __shfl(way1, src);
      const int jp = hi ? wh : wl;
      const int newr = (jp == 0) ? iRow : prowA[jp - 1];
      if (t == 0) prowA[j - 1] = newr;
      j = jp;
    }
  }

  // ---- Loss epilogue ----
  double clsum = 0.0, dsum = 0.0;
  #pragma unroll
  for (int h = 0; h < 2; ++h) {
    const int m = t + 64 * h;
    const int pr = prowA[m];
    const float* lpbm = cl + ((size_t)b * M_ + m) * CP1_;
    if (pr > 0) {
      const int r = pr - 1;
      const int g = validg[r];
      const float md = interL[g * ISTR + m] /
                       ((cntL[g] + sumpredL[m]) * 0.5f + EPS_);
      const float lpx = lpbm[semL[g]] - lseL[m];
      const float es = expSL[r * CSTR + m];
      clsum += (double)(ALPHA_ * md * (-lpx));            // alpha*dice*pos_ce
      dsum  += (double)(-es * logf(md + EPS_));           // -cls*log(dice+eps)
    } else {
      clsum += (double)((1.0f - ALPHA_) * negceL[m]);     // 0.25 * neg_ce
    }
  }
  #pragma unroll
  for (int o = 32; o; o >>= 1) {
    clsum += __shfl_xor(clsum, o);
    dsum  += __shfl_xor(dsum, o);
  }
  if (t == 0) {
    const float contrib = (float)(clsum / (double)(B_ * M_) +
                                  dsum / (double)(nvtotL + 1));
    atomicAdd(out, contrib);
  }
}

// ---------------------------------------------------------------------------
extern "C" void kernel_launch(void* const* d_in, const int* in_sizes, int n_in,
                              void* d_out, int out_size, void* d_ws, size_t ws_size,
                              hipStream_t stream) {
  const float* logits = (const float*)d_in[0];
  const float* cl     = (const float*)d_in[1];
  const int*   gt     = (const int*)d_in[2];
  const int*   semmap = (const int*)d_in[3];
  float* out = (float*)d_out;

  // workspace: cnts | baseg | ordered (ints) | interP (floats)
  int*   cnts    = (int*)d_ws;
  int*   baseg   = cnts + B_ * NCH_ * G_;
  int*   ordered = baseg + B_ * (G_ + 1);
  float* interP  = (float*)(ordered + (size_t)B_ * HW_);

  hipMemsetAsync(d_out, 0, sizeof(float), stream);
  hipLaunchKernelGGL(kH1_count, dim3(B_ * NCH_), dim3(256), 0, stream,
                     gt, cnts);
  hipLaunchKernelGGL(kH2_prefix, dim3(1), dim3(512), 0, stream,
                     cnts, baseg);
  hipLaunchKernelGGL(kH3_scatter, dim3(B_ * NCH_), dim3(256), 0, stream,
                     gt, cnts, baseg, ordered);
  hipLaunchKernelGGL(kS_gather, dim3(B_ * G_ * 2), dim3(512), 0, stream,
                     logits, ordered, baseg, interP);
  hipLaunchKernelGGL(k4_match_loss, dim3(B_), dim3(1024), 0, stream,
                     interP, cl, semmap, out);
}

// Round 7
// 212.568 us; speedup vs baseline: 1.6785x; 1.0205x over previous
//
#include <hip/hip_runtime.h>
#include <math.h>

// Problem constants (fixed shapes from the reference)
#define B_    8
#define HW_   25921        // 161*161
#define M_    128          // mask slots
#define G_    64           // GT slots
#define CP1_  134          // classes + 1
#define CLS_  133          // "no object" index = C
#define ALPHA_ 0.75f
#define EPS_   1e-5f
#define NCH_  16           // chunks per batch for counting sort
#define CHSZ_ 1621         // ceil(HW_/NCH_)
#define LCAP_ 640          // LDS staging capacity per kS sub-block

// ---------------------------------------------------------------------------
// kH1: per-(b,chunk) histogram of gt values. 128 blocks. Int LDS atomics,
// 4 sub-histograms. -> cnts[b][c][G]
// ---------------------------------------------------------------------------
__global__ __launch_bounds__(256) void kH1_count(
    const int* __restrict__ gt, int* __restrict__ cnts)
{
  __shared__ int cnt[4][G_];
  const int tid = threadIdx.x;
  const int b = blockIdx.x >> 4, c = blockIdx.x & 15;
  const int p0 = c * CHSZ_, p1 = min(p0 + CHSZ_, HW_);
  const int* gtb = gt + (size_t)b * HW_;
  for (int i = tid; i < 4 * G_; i += 256) ((int*)cnt)[i] = 0;
  __syncthreads();
  for (int p = p0 + tid; p < p1; p += 256)
    atomicAdd(&cnt[tid & 3][gtb[p]], 1);
  __syncthreads();
  if (tid < G_)
    cnts[(blockIdx.x << 6) + tid] =
      cnt[0][tid] + cnt[1][tid] + cnt[2][tid] + cnt[3][tid];
}

// ---------------------------------------------------------------------------
// kH23: fused prefix+scatter. Each of the 128 blocks recomputes the per-batch
// global prefix locally from cnts (16x64 ints, coalesced); block c==0 also
// writes baseg for kS. Then atomic-offset scatter of its chunk.
// ---------------------------------------------------------------------------
__global__ __launch_bounds__(256) void kH23_scatter(
    const int* __restrict__ gt, const int* __restrict__ cnts,
    int* __restrict__ baseg, int* __restrict__ ordered)
{
  __shared__ int off[G_];
  const int tid = threadIdx.x;
  const int b = blockIdx.x >> 4, c = blockIdx.x & 15;
  const int p0 = c * CHSZ_, p1 = min(p0 + CHSZ_, HW_);
  const int* gtb = gt + (size_t)b * HW_;

  if (tid < 64) {
    int tot = 0, before = 0;
    #pragma unroll
    for (int cp = 0; cp < NCH_; ++cp) {
      const int v = cnts[((b * NCH_ + cp) << 6) + tid];
      tot += v;
      if (cp < c) before += v;
    }
    int inc = tot;
    #pragma unroll
    for (int o = 1; o < 64; o <<= 1) {
      const int n = __shfl_up(inc, o);
      if (tid >= o) inc += n;
    }
    const int ex = inc - tot;                 // exclusive prefix over g
    off[tid] = ex + before;
    if (c == 0) {
      baseg[b * (G_ + 1) + tid] = ex;
      if (tid == 63) baseg[b * (G_ + 1) + G_] = ex + tot;
    }
  }
  __syncthreads();
  int* ob = ordered + (size_t)b * HW_;
  for (int p = p0 + tid; p < p1; p += 256) {
    const int pos = atomicAdd(&off[gtb[p]], 1);
    ob[pos] = p;
  }
}

// ---------------------------------------------------------------------------
// kS: gather pass, float4 rows. 2 sub-blocks per (b,g); stage the pixel list
// in LDS; each wave: 8 pixels/iter (2 per float4 load instr, half-wave per
// pixel), 5-level intra-32 shfl denominator, float4 register accumulator.
// Deterministic LDS tree -> interP[b][s][g][m]. No fp atomics.
// ---------------------------------------------------------------------------
__global__ __launch_bounds__(512) void kS_gather(
    const float* __restrict__ logits, const int* __restrict__ ordered,
    const int* __restrict__ baseg, float* __restrict__ interP)
{
  __shared__ float red[8][2][132];
  __shared__ int   lstL[LCAP_];
  const int tid = threadIdx.x;
  const int s = blockIdx.x & 1;
  const int g = (blockIdx.x >> 1) & 63;
  const int b = blockIdx.x >> 7;
  const int lane = tid & 63, wave = tid >> 6;
  const int ph = lane >> 5, l31 = lane & 31;

  const int s0 = baseg[b * (G_ + 1) + g];
  const int s1 = baseg[b * (G_ + 1) + g + 1];
  const int n = s1 - s0;
  const int hn = (n + 1) >> 1;
  const int start = s0 + s * hn;
  const int end = min(start + hn, s1);
  const int cnt = end - start;
  const int* lst = ordered + (size_t)b * HW_ + start;
  const float* Lb = logits + (size_t)b * HW_ * M_;

  for (int i = tid; i < cnt && i < LCAP_; i += 512) lstL[i] = lst[i];
  __syncthreads();

  float4 acc = make_float4(0.f, 0.f, 0.f, 0.f);
  for (int i = wave * 8; i < cnt; i += 64) {
    bool act[4]; float4 v[4];
    #pragma unroll
    for (int q = 0; q < 4; ++q) {
      const int li = i + 2 * q + ph;
      act[q] = li < cnt;
      const int lc = act[q] ? li : (cnt - 1);
      const int idx = (lc < LCAP_) ? lstL[lc] : lst[lc];
      v[q] = ((const float4*)(Lb + (size_t)idx * M_))[l31];
    }
    float e[4][4], sm[4];
    #pragma unroll
    for (int q = 0; q < 4; ++q) {
      e[q][0] = __expf(v[q].x); e[q][1] = __expf(v[q].y);
      e[q][2] = __expf(v[q].z); e[q][3] = __expf(v[q].w);
      sm[q] = (e[q][0] + e[q][1]) + (e[q][2] + e[q][3]);
    }
    #pragma unroll
    for (int o = 16; o; o >>= 1) {     // intra-32: stays within half-wave
      #pragma unroll
      for (int q = 0; q < 4; ++q) sm[q] += __shfl_xor(sm[q], o);
    }
    #pragma unroll
    for (int q = 0; q < 4; ++q) {
      if (act[q]) {
        const float inv = 1.0f / sm[q];
        acc.x += e[q][0] * inv;
        acc.y += e[q][1] * inv;
        acc.z += e[q][2] * inv;
        acc.w += e[q][3] * inv;
      }
    }
  }
  *(float4*)&red[wave][ph][l31 * 4] = acc;
  __syncthreads();
  if (tid < M_) {
    float sv = 0.f;
    #pragma unroll
    for (int w = 0; w < 8; ++w) sv += red[w][0][tid] + red[w][1][tid];
    interP[(((size_t)b * 2 + s) * G_ + g) * M_ + tid] = sv;
  }
}

// ---------------------------------------------------------------------------
// K4: bit-identical algorithm to R4-R6 (preserves absmax=0.015625 vertex).
// ---------------------------------------------------------------------------
#define ISTR 130   // interL stride
#define CSTR 129   // cost/expS stride

__device__ __forceinline__ double embed_idx(double a, int idx) {
  long long bl = __double_as_longlong(a);
  bl = (bl & ~0xFFll) | (long long)idx;
  return __longlong_as_double(bl);
}

__global__ __launch_bounds__(1024) void k4_match_loss(
    const float* __restrict__ interP, const float* __restrict__ cl,
    const int* __restrict__ semmap, float* __restrict__ out)
{
  __shared__ float interL[G_ * ISTR];
  __shared__ float expSL[48 * CSTR];
  __shared__ float costL[48 * CSTR];
  __shared__ float lseL[M_], negceL[M_], sumpredL[M_], cntL[G_];
  __shared__ int   semL[G_], validg[G_];
  __shared__ int   ivA[M_], prowA[M_], colofL[G_];
  __shared__ int   nvL, nvtotL;

  const int tid = threadIdx.x;
  const int b = blockIdx.x;
  const int lane = tid & 63, wave = tid >> 6;

  // ---- Phase A: semL, interL load (sum 2 partials), class log-softmax ----
  if (tid < G_) semL[tid] = semmap[b * G_ + tid];
  {
    const float* ip0 = interP + (size_t)(b * 2 + 0) * G_ * M_;
    const float* ip1 = interP + (size_t)(b * 2 + 1) * G_ * M_;
    for (int i = tid; i < G_ * M_; i += 1024) {
      const int g = i >> 7, m = i & 127;
      interL[g * ISTR + m] = ip0[i] + ip1[i];
    }
  }
  for (int r = wave; r < M_; r += 16) {
    const float* x = cl + ((size_t)b * M_ + r) * CP1_;
    float a = x[lane];
    float bb = (lane + 64  < CP1_) ? x[lane + 64]  : -1e30f;
    float cc = (lane + 128 < CP1_) ? x[lane + 128] : -1e30f;
    float mx = fmaxf(a, fmaxf(bb, cc));
    #pragma unroll
    for (int o = 32; o; o >>= 1) mx = fmaxf(mx, __shfl_xor(mx, o));
    float s = __expf(a - mx);
    if (lane + 64  < CP1_) s += __expf(bb - mx);
    if (lane + 128 < CP1_) s += __expf(cc - mx);
    #pragma unroll
    for (int o = 32; o; o >>= 1) s += __shfl_xor(s, o);
    const float lse = mx + logf(s);
    if (lane == 0) lseL[r] = lse;
    if (lane == CLS_ - 128) negceL[r] = lse - cc;   // -log_prob[.., C]
  }
  __syncthreads();

  // ---- Phase A2: wave 0: validg/nv + nvtot ----
  if (wave == 0) {
    const int sv = semL[tid];
    const unsigned long long vm = __ballot(sv >= 0);
    if (sv >= 0) {
      const int rank = __popcll(vm & ((1ull << tid) - 1ull));
      validg[rank] = tid;
    }
    if (tid == 0) nvL = (int)__popcll(vm);
    int c = 0;
    #pragma unroll
    for (int kk = 0; kk < (B_ * G_) / 64; ++kk)
      c += (semmap[tid + 64 * kk] >= 0) ? 1 : 0;
    #pragma unroll
    for (int o = 32; o; o >>= 1) c += __shfl_xor(c, o);
    if (tid == 0) nvtotL = c;
  }
  __syncthreads();
  const int nv = min(nvL, 48);

  // ---- Phase B1: sumpred, cnt, expS ----
  if (tid < M_) {
    float s = 0.f;
    for (int g = 0; g < G_; ++g) s += interL[g * ISTR + tid];
    sumpredL[tid] = s;
  } else if (tid < M_ + G_) {
    const int g = tid - M_;
    float s = 0.f;
    for (int m = 0; m < M_; ++m) s += interL[g * ISTR + m];
    cntL[g] = s;
  } else if (tid >= 256) {
    for (int i = tid - 256; i < nv * M_; i += 768) {
      const int r = i >> 7, m = i & 127;
      const int sem = semL[validg[r]];
      expSL[r * CSTR + m] =
        __expf(cl[((size_t)b * M_ + m) * CP1_ + sem] - lseL[m]);
    }
  }
  __syncthreads();

  // ---- Phase B2: cost ----
  for (int i = tid; i < nv * M_; i += 1024) {
    const int r = i >> 7, m = i & 127;
    const int g = validg[r];
    const float dice = interL[g * ISTR + m] /
                       ((cntL[g] + sumpredL[m]) * 0.5f + EPS_);
    costL[r * CSTR + m] = -(expSL[r * CSTR + m] * dice);
  }
  __syncthreads();

  if (wave != 0) return;
  const int t = tid;   // 0..63

  // ---- JV init: u=rowmin, v=col reduction, greedy tight assignment ----
  double u_reg = 0.0;
  if (t < nv) {
    float bv = 1e30f;
    for (int m = 0; m < M_; ++m) {
      const float c = costL[t * CSTR + m];
      if (c < bv) bv = c;
    }
    u_reg = (double)bv;
  }
  double v0d = 0.0, v1d = 0.0;
  {
    double m0 = 1e18, m1 = 1e18; int i0 = 0, i1 = 0;
    for (int i = 0; i < nv; ++i) {
      const double ui = __shfl(u_reg, i);
      const double c0 = (double)costL[i * CSTR + t] - ui;
      const double c1 = (double)costL[i * CSTR + t + 64] - ui;
      if (c0 < m0) { m0 = c0; i0 = i; }
      if (c1 < m1) { m1 = c1; i1 = i; }
    }
    v0d = m0; v1d = m1;
    ivA[t] = i0; ivA[t + 64] = i1;
  }
  prowA[t] = 0; prowA[t + 64] = 0;
  if (t < G_) colofL[t] = -1;
  if (t == 0) {
    unsigned long long rowfree = (nv < 64) ? ((1ull << nv) - 1ull) : ~0ull;
    for (int j = 0; j < M_; ++j) {
      const int r = ivA[j];
      if ((rowfree >> r) & 1ull) {
        rowfree &= ~(1ull << r);
        prowA[j] = r + 1;
        colofL[r] = j;
      }
    }
  }
  unsigned long long um = __ballot(t < nv && colofL[t] < 0);

  // ---- SSP for remaining free rows ----
  int way0, way1;
  while (um) {
    const int iRow = (int)__builtin_ctzll(um) + 1;
    um &= um - 1;
    double minv0 = 1e18, minv1 = 1e18;
    bool used0 = false, used1 = false;
    bool inTree = false;
    way0 = 0; way1 = 0;
    int j0 = 0, i0 = iRow;
    for (int guard = 0; guard < 2 * M_ + 4; ++guard) {
      if (j0 != 0) {
        const int src = (j0 - 1) & 63, hi = (j0 - 1) >> 6;
        if (t == src) { if (hi) used1 = true; else used0 = true; }
      }
      if (t == i0 - 1) inTree = true;
      const double ui0 = __shfl(u_reg, i0 - 1);
      const float c0 = costL[(i0 - 1) * CSTR + t];
      const float c1 = costL[(i0 - 1) * CSTR + t + 64];
      if (!used0) { const double cur = (double)c0 - ui0 - v0d; if (cur < minv0) { minv0 = cur; way0 = j0; } }
      if (!used1) { const double cur = (double)c1 - ui0 - v1d; if (cur < minv1) { minv1 = cur; way1 = j0; } }
      const double a0 = used0 ? 1e18 : minv0;
      const double a1 = used1 ? 1e18 : minv1;
      double pk = fmin(embed_idx(a0, t + 1), embed_idx(a1, t + 65));
      #pragma unroll
      for (int o = 32; o; o >>= 1) pk = fmin(pk, __shfl_xor(pk, o));
      const int j1 = (int)(__double_as_longlong(pk) & 0xFF);
      const int src1 = (j1 - 1) & 63, hi1 = (j1 - 1) >> 6;
      const double d0s = __shfl(minv0, src1);
      const double d1s = __shfl(minv1, src1);
      const double delta = hi1 ? d1s : d0s;       // exact minv[j1]
      const int pr = prowA[j1 - 1];               // prefetch + break check
      if (used0) v0d -= delta; else minv0 -= delta;
      if (used1) v1d -= delta; else minv1 -= delta;
      if (inTree) u_reg += delta;
      j0 = j1;
      if (pr == 0) break;
      i0 = pr;
    }
    // augment along 'way' chain
    int j = j0;
    for (int guard = 0; guard <= M_ && j; ++guard) {
      const int src = (j - 1) & 63, hi = (j - 1) >> 6;
      const int wl = __shfl(way0, src), wh = __shfl(way1, src);
      const int jp = hi ? wh : wl;
      const int newr = (jp == 0) ? iRow : prowA[jp - 1];
      if (t == 0) prowA[j - 1] = newr;
      j = jp;
    }
  }

  // ---- Loss epilogue ----
  double clsum = 0.0, dsum = 0.0;
  #pragma unroll
  for (int h = 0; h < 2; ++h) {
    const int m = t + 64 * h;
    const int pr = prowA[m];
    const float* lpbm = cl + ((size_t)b * M_ + m) * CP1_;
    if (pr > 0) {
      const int r = pr - 1;
      const int g = validg[r];
      const float md = interL[g * ISTR + m] /
                       ((cntL[g] + sumpredL[m]) * 0.5f + EPS_);
      const float lpx = lpbm[semL[g]] - lseL[m];
      const float es = expSL[r * CSTR + m];
      clsum += (double)(ALPHA_ * md * (-lpx));            // alpha*dice*pos_ce
      dsum  += (double)(-es * logf(md + EPS_));           // -cls*log(dice+eps)
    } else {
      clsum += (double)((1.0f - ALPHA_) * negceL[m]);     // 0.25 * neg_ce
    }
  }
  #pragma unroll
  for (int o = 32; o; o >>= 1) {
    clsum += __shfl_xor(clsum, o);
    dsum  += __shfl_xor(dsum, o);
  }
  if (t == 0) {
    const float contrib = (float)(clsum / (double)(B_ * M_) +
                                  dsum / (double)(nvtotL + 1));
    atomicAdd(out, contrib);
  }
}

// ---------------------------------------------------------------------------
extern "C" void kernel_launch(void* const* d_in, const int* in_sizes, int n_in,
                              void* d_out, int out_size, void* d_ws, size_t ws_size,
                              hipStream_t stream) {
  const float* logits = (const float*)d_in[0];
  const float* cl     = (const float*)d_in[1];
  const int*   gt     = (const int*)d_in[2];
  const int*   semmap = (const int*)d_in[3];
  float* out = (float*)d_out;

  // workspace: cnts | baseg | ordered (ints) | interP (floats)
  int*   cnts    = (int*)d_ws;
  int*   baseg   = cnts + B_ * NCH_ * G_;
  int*   ordered = baseg + B_ * (G_ + 1);
  float* interP  = (float*)(ordered + (size_t)B_ * HW_);

  hipMemsetAsync(d_out, 0, sizeof(float), stream);
  hipLaunchKernelGGL(kH1_count, dim3(B_ * NCH_), dim3(256), 0, stream,
                     gt, cnts);
  hipLaunchKernelGGL(kH23_scatter, dim3(B_ * NCH_), dim3(256), 0, stream,
                     gt, cnts, baseg, ordered);
  hipLaunchKernelGGL(kS_gather, dim3(B_ * G_ * 2), dim3(512), 0, stream,
                     logits, ordered, baseg, interP);
  hipLaunchKernelGGL(k4_match_loss, dim3(B_), dim3(1024), 0, stream,
                     interP, cl, semmap, out);
}